// Round 11
// baseline (532.043 us; speedup 1.0000x reference)
//
#include <hip/hip_runtime.h>

typedef __bf16 bf16_t;
typedef __bf16 bf16x8 __attribute__((ext_vector_type(8)));
typedef float f32x16 __attribute__((ext_vector_type(16)));
typedef float f32x4 __attribute__((ext_vector_type(4)));
typedef int i32x8 __attribute__((ext_vector_type(8)));

#define NB 8
#define NC 256
#define NN 4096

__device__ __forceinline__ f32x16 mfma32(bf16x8 a, bf16x8 b, f32x16 c) {
  return __builtin_amdgcn_mfma_f32_32x32x16_bf16(a, b, c, 0, 0, 0);
}

// K=128 fp8 matmul via MX-scaled MFMA with scale = 1.0 (E8M0 byte 127)
__device__ __forceinline__ f32x4 mfma128(i32x8 a, i32x8 b, f32x4 c) {
  return __builtin_amdgcn_mfma_scale_f32_16x16x128_f8f6f4(
      a, b, c, 0, 0, 0, 0x7f7f7f7f, 0, 0x7f7f7f7f);
}

__device__ __forceinline__ void gload_lds16(const void* g, void* l) {
  __builtin_amdgcn_global_load_lds((const __attribute__((address_space(1))) void*)g,
                                   (__attribute__((address_space(3))) void*)l, 16, 0, 0);
}

__device__ __forceinline__ unsigned int packbf2(float lo, float hi) {
  union { bf16_t h; unsigned short s; } a, b;
  a.h = (bf16_t)lo; b.h = (bf16_t)hi;
  return (unsigned int)a.s | ((unsigned int)b.s << 16);
}

__device__ __forceinline__ f32x16 fzero() {
  f32x16 z;
#pragma unroll
  for (int r = 0; r < 16; r++) z[r] = 0.f;
  return z;
}

// post-QK score scale: (1/W) * log2(e)  (softmax in exp2 domain, no shift: P~1)
#define QSCALE (0.015625f * 1.44269504088896f)

// ---------------- Kernel 1: convert weights to bf16 ---------------------------
__global__ void kconv_w(const float* __restrict__ Wq, const float* __restrict__ bq,
                        const float* __restrict__ Wk, const float* __restrict__ bk,
                        const float* __restrict__ Wv, const float* __restrict__ bv,
                        bf16_t* __restrict__ Wc, float* __restrict__ bc) {
  int idx = blockIdx.x * 256 + threadIdx.x;   // 768*256 total
  int d = idx >> 8;
  float w;
  if (d < 256)      w = Wq[idx];
  else if (d < 512) w = Wk[idx - 65536];
  else              w = Wv[idx - 131072];
  Wc[idx] = (bf16_t)w;
  if (idx < 768) {
    float v = idx < 256 ? bq[idx] : (idx < 512 ? bk[idx - 256] : bv[idx - 512]);
    bc[idx] = v;
  }
}

// ---------------- Kernel 2: x [B][C][N] f32 -> fT [B][N][C] bf16 -------------
__global__ void ktranspose(const float* __restrict__ x, bf16_t* __restrict__ fT) {
  __shared__ float tile[64][65];
  int bid = blockIdx.x;
  int b = bid >> 8;
  int r = bid & 255;
  int n0 = (r >> 2) * 64;
  int c0 = (r & 3) * 64;
  int t = threadIdx.x;
  const float* xb = x + ((long)b * NC + c0) * NN + n0;
  int lr = t >> 4;
  int lc = (t & 15) * 4;
#pragma unroll
  for (int i = 0; i < 4; i++) {
    float4 v4 = *(const float4*)(xb + (long)(lr + i * 16) * NN + lc);
    tile[lr + i * 16][lc + 0] = v4.x; tile[lr + i * 16][lc + 1] = v4.y;
    tile[lr + i * 16][lc + 2] = v4.z; tile[lr + i * 16][lc + 3] = v4.w;
  }
  __syncthreads();
  int nl = t >> 2;
  int cc = (t & 3) * 16;
  bf16_t* dst = fT + ((long)b * NN + n0 + nl) * NC + c0 + cc;
  union { bf16_t h[8]; uint4 u; } p0, p1;
#pragma unroll
  for (int j = 0; j < 8; j++) p0.h[j] = (bf16_t)tile[cc + j][nl];
#pragma unroll
  for (int j = 0; j < 8; j++) p1.h[j] = (bf16_t)tile[cc + 8 + j][nl];
  *(uint4*)dst = p0.u;
  *(uint4*)(dst + 8) = p1.u;
}

// ---------------- Kernel 3: projection GEMM [768,256]x[256,32768] ------------
// outputs (fp8 e4m3), frag-major for 16x16x128 scaled mfma (plane-split 16B):
//  q tiles Kd[b][nt32]: byte (2h+cc)*2048 + (e>>4)*1024 + l*16 + (e&15)
//     = q[n=16h+(l&15)][c=cc*128+((l>>4)&3)*32+e]
//  v super-tiles vD[b][ns128] 32KB: byte ct*2048 + ((nn>>6)&1)*1024
//     + ((c&15)+16*((nn>>2)&3))*16 + 4*((nn>>4)&3) + (nn&3)   (n-perm baked)
//  k as [B][N][C]
__global__ __launch_bounds__(256) void kproj(const bf16_t* __restrict__ Wc, const float* __restrict__ bc,
                                             const bf16_t* __restrict__ fT,
                                             unsigned char* __restrict__ qT8, unsigned char* __restrict__ kT8,
                                             unsigned char* __restrict__ vO8) {
  __shared__ bf16_t ft[128 * 256];  // XOR-swizzled rows, 64KB
  int bid = blockIdx.x;
  int mt = bid % 6;
  int nb = bid / 6;
  int d0 = mt * 128;
  int gc0 = nb * 128;
  int b = gc0 >> 12;
  int n0 = gc0 & 4095;
  int t = threadIdx.x, lane = t & 63, w = t >> 6;
  int lm = lane & 31, g = lane >> 5;
  const bf16_t* ftb = fT + ((long)b * NN + n0) * NC;
#pragma unroll
  for (int i2 = 0; i2 < 16; i2++) {
    int call = w * 16 + i2;
    int p = call * 1024 + lane * 16;
    int n = p >> 9, cb = p & 511;
    int scb = cb ^ ((n & 7) << 4);
    gload_lds16(ftb + (long)n * NC + (scb >> 1), (char*)ft + call * 1024);
  }
  __syncthreads();

  f32x16 acc00 = fzero(), acc01 = fzero(), acc10 = fzero(), acc11 = fzero();
  int dbase = d0 + (w >> 1) * 64;
  int nbase = (w & 1) * 64;
  const bf16_t* wr = Wc + (long)dbase * NC;
#pragma unroll
  for (int j = 0; j < 16; j++) {
    int cc = j * 16 + g * 8;
    bf16x8 a0 = *(const bf16x8*)(wr + (long)lm * NC + cc);
    bf16x8 a1 = *(const bf16x8*)(wr + (long)(lm + 32) * NC + cc);
    int row0 = nbase + lm;
    bf16x8 b0 = *(const bf16x8*)((char*)ft + row0 * 512 + ((cc * 2) ^ ((row0 & 7) << 4)));
    int row1 = row0 + 32;
    bf16x8 b1 = *(const bf16x8*)((char*)ft + row1 * 512 + ((cc * 2) ^ ((row1 & 7) << 4)));
    acc00 = mfma32(a0, b0, acc00);
    acc01 = mfma32(a0, b1, acc01);
    acc10 = mfma32(a1, b0, acc10);
    acc11 = mfma32(a1, b1, acc11);
  }

  auto epi = [&](f32x16 a, int dt, int nt2) {
    int db = dbase + dt * 32;
    int colg = n0 + nbase + nt2 * 32 + lm;
    if (mt >= 4) {        // v rows -> frag-major vD (byte stores, perm baked)
      int nn = colg & 127;
      long base = ((long)b * 32 + (colg >> 7)) * 32768 +
                  ((nn >> 6) & 1) * 1024 + 16 * ((nn >> 2) & 3) * 16 +
                  4 * ((nn >> 4) & 3) + (nn & 3);
#pragma unroll
      for (int r = 0; r < 16; r++) {
        int d = db + (r & 3) + 8 * (r >> 2) + 4 * g;
        int c = d - 512;
        unsigned int f8 = __builtin_amdgcn_cvt_pk_fp8_f32(a[r] + bc[d], 0.f, 0, false);
        vO8[base + (c >> 4) * 2048 + (c & 15) * 16] = (unsigned char)f8;
      }
    } else if (mt < 2) {  // q rows -> frag-major Kd (u32 stores)
      long tb = ((long)b * 128 + (colg >> 5)) * 8192;
      int h = (colg >> 4) & 1;
      int l = (colg & 15) + 16 * ((db >> 5) & 3);
      int cc = db >> 7;
      long ob = tb + (2 * h + cc) * 2048 + l * 16;
#pragma unroll
      for (int t4 = 0; t4 < 4; t4++) {
        int cb = db + 8 * t4 + 4 * g;
        unsigned int pk = __builtin_amdgcn_cvt_pk_fp8_f32(a[4 * t4 + 0] + bc[cb + 0],
                                                          a[4 * t4 + 1] + bc[cb + 1], 0, false);
        pk = __builtin_amdgcn_cvt_pk_fp8_f32(a[4 * t4 + 2] + bc[cb + 2],
                                             a[4 * t4 + 3] + bc[cb + 3], pk, true);
        *(unsigned int*)(qT8 + ob + (t4 >> 1) * 1024 + 8 * (t4 & 1) + 4 * g) = pk;
      }
    } else {              // k rows -> [B][N][C] fp8 (pair ushort stores)
      unsigned char* dst = kT8 + ((long)b * NN + colg) * 256 - 256;
#pragma unroll
      for (int r2 = 0; r2 < 8; r2++) {
        int r = r2 * 2;
        int d = db + (r & 3) + 8 * (r >> 2) + 4 * g;
        unsigned int pk = __builtin_amdgcn_cvt_pk_fp8_f32(a[r] + bc[d], a[r + 1] + bc[d + 1], 0, false);
        *(unsigned short*)(dst + d) = (unsigned short)pk;
      }
    }
  };
  epi(acc00, 0, 0); epi(acc01, 0, 1); epi(acc10, 1, 0); epi(acc11, 1, 1);
}

// ---------------- Kernel 4: fp8 flash attention, K=128 scaled MFMA -----------
// superstep = 128 n: 4 subtiles {stageK, stageV-part, 4 QK mfma, softmax->pf},
// then one 16-mfma PV burst. All LDS reads contiguous b128 (plane-split frags).
__global__ __launch_bounds__(512, 4) void kattn(const unsigned char* __restrict__ qT8,
                                                const unsigned char* __restrict__ kT8,
                                                const unsigned char* __restrict__ vO8,
                                                char* __restrict__ R0, char* __restrict__ R1, int nss) {
  __shared__ unsigned char Kt[2][8192];
  __shared__ unsigned char Vs[2][32768];
  int bid = blockIdx.x;
  int b = bid & 7;
  int mtile = (bid >> 3) & 31;
  int split = bid >> 8;
  int t = threadIdx.x, lane = t & 63, w = t >> 6;   // 8 waves
  int l4 = lane & 15, q = (lane >> 4) & 3;
  int mw = mtile * 128 + w * 16;
  const unsigned char* qb = qT8 + (long)b * 1048576;    // 128 q-tiles x 8192
  const unsigned char* vtb = vO8 + (long)b * 1048576;   // 32 super-tiles x 32768
  int sub0 = split * nss * 4;
  int sup0 = split * nss;

  // qf: B-frags (flash-query = k-proj), col m = l4, k=c = cc*128 + q*32 + e
  i32x8 qf0, qf1;
  {
    const unsigned char* kb = kT8 + ((long)b * NN + mw + l4) * 256 + q * 32;
    union { uint4 u[2]; i32x8 v; } r;
    r.u[0] = *(const uint4*)(kb);      r.u[1] = *(const uint4*)(kb + 16);
    qf0 = r.v;
    r.u[0] = *(const uint4*)(kb + 128); r.u[1] = *(const uint4*)(kb + 144);
    qf1 = r.v;
  }

  f32x4 acc[16];
#pragma unroll
  for (int ct = 0; ct < 16; ct++) acc[ct] = f32x4{0.f, 0.f, 0.f, 0.f};
  float lsum = 0.f;
  unsigned int pf[8];

  auto stageK = [&](int gi, int bufi) {   // 8KB: one 16B gload per thread
    gload_lds16(qb + (long)gi * 8192 + t * 16, &Kt[bufi][t * 16]);
  };
  auto stageVp = [&](int gs, int bufi, int part) {  // 8KB part of 32KB super
    gload_lds16(vtb + (long)gs * 32768 + part * 8192 + t * 16,
                &Vs[bufi][part * 8192 + t * 16]);
  };
  auto ldfrag = [&](const unsigned char* fb) {
    union { uint4 u[2]; i32x8 v; } r;
    r.u[0] = *(const uint4*)(fb + lane * 16);
    r.u[1] = *(const uint4*)(fb + 1024 + lane * 16);
    return r.v;
  };

  stageK(sub0, 0);
#pragma unroll
  for (int p = 0; p < 4; p++) stageVp(sup0, 0, p);
  __syncthreads();

#pragma unroll 1
  for (int s = 0; s < nss; s++) {
    int snext = sup0 + (s + 1 < nss ? s + 1 : s);
    int sbuf = s & 1;
#pragma unroll
    for (int tt = 0; tt < 4; tt++) {
      int li = 4 * s + tt;
      if (li + 1 < 4 * nss) stageK(sub0 + li + 1, (tt & 1) ^ 1);
      stageVp(snext, sbuf ^ 1, tt);
      // ---- QK: 4 x K=128 mfma from Kt[tt&1] ----
      __builtin_amdgcn_s_setprio(1);
      const unsigned char* kbase = &Kt[tt & 1][0];
      f32x4 s0 = f32x4{0.f, 0.f, 0.f, 0.f}, s1 = f32x4{0.f, 0.f, 0.f, 0.f};
      s0 = mfma128(ldfrag(kbase), qf0, s0);
      s0 = mfma128(ldfrag(kbase + 2048), qf1, s0);
      s1 = mfma128(ldfrag(kbase + 4096), qf0, s1);
      s1 = mfma128(ldfrag(kbase + 6144), qf1, s1);
      __builtin_amdgcn_s_setprio(0);
      // ---- softmax (exp2 domain); e-slots land exactly in pf[2t],pf[2t+1] ----
      float e0[4], e1[4];
#pragma unroll
      for (int r = 0; r < 4; r++) {
        e0[r] = __builtin_amdgcn_exp2f(s0[r] * QSCALE);
        e1[r] = __builtin_amdgcn_exp2f(s1[r] * QSCALE);
      }
      lsum += ((e0[0] + e0[1]) + (e0[2] + e0[3])) + ((e1[0] + e1[1]) + (e1[2] + e1[3]));
      unsigned int u0 = __builtin_amdgcn_cvt_pk_fp8_f32(e0[0], e0[1], 0, false);
      pf[2 * tt] = __builtin_amdgcn_cvt_pk_fp8_f32(e0[2], e0[3], u0, true);
      unsigned int u1 = __builtin_amdgcn_cvt_pk_fp8_f32(e1[0], e1[1], 0, false);
      pf[2 * tt + 1] = __builtin_amdgcn_cvt_pk_fp8_f32(e1[2], e1[3], u1, true);
      if (tt == 3) {
        // ---- PV burst: 16 x K=128 mfma from Vs[sbuf] ----
        union { unsigned int u[8]; i32x8 v; } pB;
#pragma unroll
        for (int j = 0; j < 8; j++) pB.u[j] = pf[j];
        __builtin_amdgcn_s_setprio(1);
        const unsigned char* vbase = &Vs[sbuf][0];
#pragma unroll
        for (int ct = 0; ct < 16; ct++)
          acc[ct] = mfma128(ldfrag(vbase + ct * 2048), pB.v, acc[ct]);
        __builtin_amdgcn_s_setprio(0);
      }
      __syncthreads();
    }
  }
  // ---- epilogue: reduce lsum over q-groups; write bf16 partials ----
  float ltot = lsum + __shfl_xor(lsum, 16, 64);
  ltot += __shfl_xor(ltot, 32, 64);
  char* R = split ? R1 : R0;
  unsigned int* PP = (unsigned int*)R;
  float* MLf = (float*)(R + 16777216);
  int mg = ((b * 32 + mtile) << 3) + w;
  if (lane < 16) MLf[mg * 16 + lane] = ltot;
#pragma unroll
  for (int ct = 0; ct < 16; ct++) {
    uint2 pk;
    pk.x = packbf2(acc[ct][0], acc[ct][1]);
    pk.y = packbf2(acc[ct][2], acc[ct][3]);
    *(uint2*)(PP + (mg * 16 + ct) * 128 + lane * 2) = pk;
  }
}

// ---------------- Kernel 5: combine splits, normalize, gamma*o + x -----------
__global__ __launch_bounds__(256) void kcombine(const char* __restrict__ R0, const char* __restrict__ R1,
                                                int nsplit, const float* __restrict__ x,
                                                const float* __restrict__ gma, float* __restrict__ out) {
  int tid = blockIdx.x * 256 + threadIdx.x;   // 4.19M threads, 2 outputs each
  const unsigned int* P0 = (const unsigned int*)R0;
  const float* ML0 = (const float*)(R0 + 16777216);
  int mg = tid >> 11;
  int ct = (tid >> 7) & 15;
  int lane = (tid >> 1) & 63;
  int rr = tid & 1;
  int b = mg >> 8, mtile = (mg >> 3) & 31, w = mg & 7;
  int m = mtile * 128 + w * 16 + (lane & 15);
  int c0 = ct * 16 + ((lane >> 4) & 3) * 4 + rr * 2;
  unsigned int p0 = P0[tid];
  float ox = __uint_as_float(p0 << 16);
  float oy = __uint_as_float(p0 & 0xffff0000u);
  float L = ML0[mg * 16 + (lane & 15)];
  if (nsplit == 2) {      // no shift: splits combine by plain addition
    const unsigned int* P1 = (const unsigned int*)R1;
    const float* ML1 = (const float*)(R1 + 16777216);
    unsigned int p1 = P1[tid];
    ox += __uint_as_float(p1 << 16);
    oy += __uint_as_float(p1 & 0xffff0000u);
    L += ML1[mg * 16 + (lane & 15)];
  }
  float sc = gma[0] / L;
  long o0 = ((long)(b * NC + c0)) * NN + m;
  out[o0] = ox * sc + x[o0];
  out[o0 + NN] = oy * sc + x[o0 + NN];
}

extern "C" void kernel_launch(void* const* d_in, const int* in_sizes, int n_in,
                              void* d_out, int out_size, void* d_ws, size_t ws_size,
                              hipStream_t stream) {
  const float* x   = (const float*)d_in[0];
  const float* Wq  = (const float*)d_in[1];
  const float* bq  = (const float*)d_in[2];
  const float* Wk  = (const float*)d_in[3];
  const float* bk  = (const float*)d_in[4];
  const float* Wv  = (const float*)d_in[5];
  const float* bv  = (const float*)d_in[6];
  const float* gma = (const float*)d_in[7];
  float* out = (float*)d_out;
  char* ws = (char*)d_ws;
  // layout (bytes): qT8 8.39M | kT8 8.39M | vO8 8.39M | fT 16.78M | Wc | bc | R1
  unsigned char* qT8 = (unsigned char*)(ws);
  unsigned char* kT8 = (unsigned char*)(ws + 8388608);
  unsigned char* vO8 = (unsigned char*)(ws + 16777216);
  bf16_t* fT = (bf16_t*)(ws + 25165824);
  bf16_t* Wc = (bf16_t*)(ws + 41943040);
  float*  bc = (float*)(ws + 42336256);
  char* R0 = ws + 25165824;         // reuses fT + Wc/bc (dead after kproj)
  char* R1 = ws + 42340352;
  size_t need2 = 42340352 + 16908288;
  int nsplit = (ws_size >= need2) ? 2 : 1;

  kconv_w<<<768, 256, 0, stream>>>(Wq, bq, Wk, bk, Wv, bv, Wc, bc);
  ktranspose<<<2048, 256, 0, stream>>>(x, fT);
  kproj<<<1536, 256, 0, stream>>>(Wc, bc, fT, qT8, kT8, vO8);
  kattn<<<256 * nsplit, 512, 0, stream>>>(qT8, kT8, vO8, R0, R1, 32 / nsplit);
  kcombine<<<16384, 256, 0, stream>>>(R0, R1, nsplit, x, gma, out);
}

// Round 12
// 287.945 us; speedup vs baseline: 1.8477x; 1.8477x over previous
//
#include <hip/hip_runtime.h>

typedef __bf16 bf16_t;
typedef __bf16 bf16x8 __attribute__((ext_vector_type(8)));
typedef float f32x16 __attribute__((ext_vector_type(16)));
typedef float f32x4 __attribute__((ext_vector_type(4)));

#define NB 8
#define NC 256
#define NN 4096

__device__ __forceinline__ f32x16 mfma32(bf16x8 a, bf16x8 b, f32x16 c) {
  return __builtin_amdgcn_mfma_f32_32x32x16_bf16(a, b, c, 0, 0, 0);
}

__device__ __forceinline__ f32x4 mfma16(uint2 a, uint2 b, f32x4 c) {
  union { uint2 u; long long l; } A, B;
  A.u = a; B.u = b;
  return __builtin_amdgcn_mfma_f32_16x16x32_fp8_fp8(A.l, B.l, c, 0, 0, 0);
}

__device__ __forceinline__ void gload_lds16(const void* g, void* l) {
  __builtin_amdgcn_global_load_lds((const __attribute__((address_space(1))) void*)g,
                                   (__attribute__((address_space(3))) void*)l, 16, 0, 0);
}

__device__ __forceinline__ unsigned int packbf2(float lo, float hi) {
  union { bf16_t h; unsigned short s; } a, b;
  a.h = (bf16_t)lo; b.h = (bf16_t)hi;
  return (unsigned int)a.s | ((unsigned int)b.s << 16);
}

__device__ __forceinline__ f32x16 fzero() {
  f32x16 z;
#pragma unroll
  for (int r = 0; r < 16; r++) z[r] = 0.f;
  return z;
}

// post-QK score scale: (1/W) * log2(e)  (softmax in exp2 domain, no shift: P~1)
#define QSCALE (0.015625f * 1.44269504088896f)

// ---------------- Kernel 1: convert weights to bf16 ---------------------------
__global__ void kconv_w(const float* __restrict__ Wq, const float* __restrict__ bq,
                        const float* __restrict__ Wk, const float* __restrict__ bk,
                        const float* __restrict__ Wv, const float* __restrict__ bv,
                        bf16_t* __restrict__ Wc, float* __restrict__ bc) {
  int idx = blockIdx.x * 256 + threadIdx.x;   // 768*256 total
  int d = idx >> 8;
  float w;
  if (d < 256)      w = Wq[idx];
  else if (d < 512) w = Wk[idx - 65536];
  else              w = Wv[idx - 131072];
  Wc[idx] = (bf16_t)w;
  if (idx < 768) {
    float v = idx < 256 ? bq[idx] : (idx < 512 ? bk[idx - 256] : bv[idx - 512]);
    bc[idx] = v;
  }
}

// ---------------- Kernel 2: x [B][C][N] f32 -> fT [B][N][C] bf16 -------------
__global__ void ktranspose(const float* __restrict__ x, bf16_t* __restrict__ fT) {
  __shared__ float tile[64][65];
  int bid = blockIdx.x;
  int b = bid >> 8;
  int r = bid & 255;
  int n0 = (r >> 2) * 64;
  int c0 = (r & 3) * 64;
  int t = threadIdx.x;
  const float* xb = x + ((long)b * NC + c0) * NN + n0;
  int lr = t >> 4;
  int lc = (t & 15) * 4;
#pragma unroll
  for (int i = 0; i < 4; i++) {
    float4 v4 = *(const float4*)(xb + (long)(lr + i * 16) * NN + lc);
    tile[lr + i * 16][lc + 0] = v4.x; tile[lr + i * 16][lc + 1] = v4.y;
    tile[lr + i * 16][lc + 2] = v4.z; tile[lr + i * 16][lc + 3] = v4.w;
  }
  __syncthreads();
  int nl = t >> 2;
  int cc = (t & 3) * 16;
  bf16_t* dst = fT + ((long)b * NN + n0 + nl) * NC + c0 + cc;
  union { bf16_t h[8]; uint4 u; } p0, p1;
#pragma unroll
  for (int j = 0; j < 8; j++) p0.h[j] = (bf16_t)tile[cc + j][nl];
#pragma unroll
  for (int j = 0; j < 8; j++) p1.h[j] = (bf16_t)tile[cc + 8 + j][nl];
  *(uint4*)dst = p0.u;
  *(uint4*)(dst + 8) = p1.u;
}

// ---------------- Kernel 3: projection GEMM [768,256]x[256,32768] ------------
// XCD-aware: the 6 blocks sharing one fT tile differ by 256 (same XCD -> L2 hit)
// outputs (fp8 e4m3), frag-major for 16x16x32 mfma:
//   q tiles Kd[b][nt]: byte (j*2+h)*512 + l*8 + e = q[n=16h+(l&15)][c=j*32+(l>>4)*8+e]
//   v tiles vD[b][nt]: byte ct*512 + l*8 + e = v[c=ct*16+(l&15)][n=16(e>>2)+4(l>>4)+(e&3)]
//   k as [B][N][C]
__global__ __launch_bounds__(256) void kproj(const bf16_t* __restrict__ Wc, const float* __restrict__ bc,
                                             const bf16_t* __restrict__ fT,
                                             unsigned char* __restrict__ qT8, unsigned char* __restrict__ kT8,
                                             unsigned char* __restrict__ vO8) {
  __shared__ bf16_t ft[128 * 256];  // XOR-swizzled rows, 64KB
  int bid = blockIdx.x;
  int mt = bid >> 8;          // 0..5
  int nb = bid & 255;         // 0..255: sharers of one fT tile are +256 apart
  int d0 = mt * 128;
  int gc0 = nb * 128;
  int b = gc0 >> 12;
  int n0 = gc0 & 4095;
  int t = threadIdx.x, lane = t & 63, w = t >> 6;
  int lm = lane & 31, g = lane >> 5;
  const bf16_t* ftb = fT + ((long)b * NN + n0) * NC;
#pragma unroll
  for (int i2 = 0; i2 < 16; i2++) {
    int call = w * 16 + i2;
    int p = call * 1024 + lane * 16;
    int n = p >> 9, cb = p & 511;
    int scb = cb ^ ((n & 7) << 4);
    gload_lds16(ftb + (long)n * NC + (scb >> 1), (char*)ft + call * 1024);
  }
  __syncthreads();

  f32x16 acc00 = fzero(), acc01 = fzero(), acc10 = fzero(), acc11 = fzero();
  int dbase = d0 + (w >> 1) * 64;
  int nbase = (w & 1) * 64;
  const bf16_t* wr = Wc + (long)dbase * NC;
#pragma unroll
  for (int j = 0; j < 16; j++) {
    int cc = j * 16 + g * 8;
    bf16x8 a0 = *(const bf16x8*)(wr + (long)lm * NC + cc);
    bf16x8 a1 = *(const bf16x8*)(wr + (long)(lm + 32) * NC + cc);
    int row0 = nbase + lm;
    bf16x8 b0 = *(const bf16x8*)((char*)ft + row0 * 512 + ((cc * 2) ^ ((row0 & 7) << 4)));
    int row1 = row0 + 32;
    bf16x8 b1 = *(const bf16x8*)((char*)ft + row1 * 512 + ((cc * 2) ^ ((row1 & 7) << 4)));
    acc00 = mfma32(a0, b0, acc00);
    acc01 = mfma32(a0, b1, acc01);
    acc10 = mfma32(a1, b0, acc10);
    acc11 = mfma32(a1, b1, acc11);
  }

  auto epi = [&](f32x16 a, int dt, int nt2) {
    int db = dbase + dt * 32;
    int colg = n0 + nbase + nt2 * 32 + lm;
    long tb = ((long)b * 128 + (colg >> 5)) * 8192;
    int n5 = colg & 31;
    if (mt >= 4) {        // v rows -> frag-major fp8 vD (byte stores)
      int q5 = (n5 >> 2) & 3;
      int e5 = ((n5 >> 4) << 2) + (n5 & 3);
      int ct0 = (db - 512) >> 4;
#pragma unroll
      for (int r = 0; r < 16; r++) {
        int d = db + (r & 3) + 8 * (r >> 2) + 4 * g;
        int ct = ct0 + (r >> 3);
        int kq = (r & 3) + 8 * ((r >> 2) & 1) + 4 * g;
        unsigned int f8 = __builtin_amdgcn_cvt_pk_fp8_f32(a[r] + bc[d], 0.f, 0, false);
        vO8[tb + (ct * 64 + q5 * 16 + kq) * 8 + e5] = (unsigned char)f8;
      }
    } else if (mt < 2) {  // q rows -> frag-major fp8 Kd (u32 stores of 4 channels)
      int h = (n5 >> 4) & 1;
      int nr = n5 & 15;
      int j = db >> 5;
#pragma unroll
      for (int t4 = 0; t4 < 4; t4++) {
        int cb = db + 8 * t4 + 4 * g;
        unsigned int pk = __builtin_amdgcn_cvt_pk_fp8_f32(a[4 * t4 + 0] + bc[cb + 0],
                                                          a[4 * t4 + 1] + bc[cb + 1], 0, false);
        pk = __builtin_amdgcn_cvt_pk_fp8_f32(a[4 * t4 + 2] + bc[cb + 2],
                                             a[4 * t4 + 3] + bc[cb + 3], pk, true);
        *(unsigned int*)(qT8 + tb + (j * 2 + h) * 512 + (t4 * 16 + nr) * 8 + 4 * g) = pk;
      }
    } else {              // k rows -> [B][N][C] fp8 (pair ushort stores)
      unsigned char* dst = kT8 + ((long)b * NN + colg) * 256 - 256;
#pragma unroll
      for (int r2 = 0; r2 < 8; r2++) {
        int r = r2 * 2;
        int d = db + (r & 3) + 8 * (r >> 2) + 4 * g;
        unsigned int pk = __builtin_amdgcn_cvt_pk_fp8_f32(a[r] + bc[d], a[r + 1] + bc[d + 1], 0, false);
        *(unsigned short*)(dst + d) = (unsigned short)pk;
      }
    }
  };
  epi(acc00, 0, 0); epi(acc01, 0, 1); epi(acc10, 1, 0); epi(acc11, 1, 1);
}

// ---------------- Kernel 4: fp8 flash attention, 16x16 frags, 8 waves --------
// R10 structure + 2 tiles per barrier (4-slot K/V rings): halves the per-iter
// vmcnt(0)+barrier convoy. No carried register state across barriers.
__global__ __launch_bounds__(512, 4) void kattn(const unsigned char* __restrict__ qT8,
                                                const unsigned char* __restrict__ kT8,
                                                const unsigned char* __restrict__ vO8,
                                                char* __restrict__ R0, char* __restrict__ R1, int iters) {
  __shared__ unsigned char Kt[4][8192];   // frag-major fp8 (q-projection tiles)
  __shared__ unsigned char Vt[4][8192];
  int bid = blockIdx.x;
  int b = bid & 7;
  int mtile = (bid >> 3) & 31;
  int split = bid >> 8;
  int nt0 = split * iters;
  int t = threadIdx.x, lane = t & 63, w = t >> 6;   // 8 waves
  int l4 = lane & 15, q = (lane >> 4) & 3;
  int mw = mtile * 128 + w * 16;
  const unsigned char* qb = qT8 + (long)b * 1048576;    // 128 tiles x 8192 B
  const unsigned char* vtb = vO8 + (long)b * 1048576;

  // B-frags of the flash-query (k-projection), col m = l4, k = q*8+e
  uint2 qf[8];
  const unsigned char* kb = kT8 + ((long)b * NN + mw + l4) * 256 + q * 8;
#pragma unroll
  for (int j = 0; j < 8; j++) qf[j] = *(const uint2*)(kb + j * 32);

  f32x4 acc[16];
#pragma unroll
  for (int ct = 0; ct < 16; ct++) acc[ct] = f32x4{0.f, 0.f, 0.f, 0.f};
  float lsum = 0.f;

  auto stageK = [&](int nt, int slot) {
    gload_lds16(qb + (long)(nt0 + nt) * 8192 + w * 1024 + lane * 16, &Kt[slot][w * 1024]);
  };
  auto stageV = [&](int nt, int slot) {
    gload_lds16(vtb + (long)(nt0 + nt) * 8192 + w * 1024 + lane * 16, &Vt[slot][w * 1024]);
  };
  auto tilework = [&](int slot) {
    // QK^T (swapped): S'_h[n16][m16], h=0,1 ; conflict-free b64 frag reads
    __builtin_amdgcn_s_setprio(1);
    const unsigned char* kbase = &Kt[slot][0] + lane * 8;
    f32x4 s0 = f32x4{0.f, 0.f, 0.f, 0.f}, s1 = f32x4{0.f, 0.f, 0.f, 0.f};
#pragma unroll
    for (int j = 0; j < 8; j++) {
      uint2 a0 = *(const uint2*)(kbase + (2 * j) * 512);
      s0 = mfma16(a0, qf[j], s0);
      uint2 a1 = *(const uint2*)(kbase + (2 * j + 1) * 512);
      s1 = mfma16(a1, qf[j], s1);
    }
    __builtin_amdgcn_s_setprio(0);
    // softmax (exp2 domain, no shift); lane holds 8 of 32 n's
    float e[8];
#pragma unroll
    for (int r = 0; r < 4; r++) {
      e[r] = __builtin_amdgcn_exp2f(s0[r] * QSCALE);
      e[4 + r] = __builtin_amdgcn_exp2f(s1[r] * QSCALE);
    }
    lsum += ((e[0] + e[1]) + (e[2] + e[3])) + ((e[4] + e[5]) + (e[6] + e[7]));
    uint2 pf;
    pf.x = __builtin_amdgcn_cvt_pk_fp8_f32(e[0], e[1], 0, false);
    pf.x = __builtin_amdgcn_cvt_pk_fp8_f32(e[2], e[3], pf.x, true);
    pf.y = __builtin_amdgcn_cvt_pk_fp8_f32(e[4], e[5], 0, false);
    pf.y = __builtin_amdgcn_cvt_pk_fp8_f32(e[6], e[7], pf.y, true);
    // PV: O[c][m] += V . P, 16 c-frags, K=32 (full n-tile)
    __builtin_amdgcn_s_setprio(1);
    const unsigned char* vbase = &Vt[slot][0] + lane * 8;
#pragma unroll
    for (int ct = 0; ct < 16; ct++) {
      uint2 va = *(const uint2*)(vbase + ct * 512);
      acc[ct] = mfma16(va, pf, acc[ct]);
    }
    __builtin_amdgcn_s_setprio(0);
  };

  stageK(0, 0); stageV(0, 0);
  stageK(1, 1); stageV(1, 1);
  __syncthreads();

#pragma unroll 1
  for (int s = 0; s < iters; s += 2) {
    if (s + 2 < iters) {        // iters even: s+3 in range whenever s+2 is
      stageK(s + 2, (s + 2) & 3); stageV(s + 2, (s + 2) & 3);
      stageK(s + 3, (s + 3) & 3); stageV(s + 3, (s + 3) & 3);
    }
    tilework(s & 3);
    tilework((s + 1) & 3);
    __syncthreads();
  }
  // ---- epilogue: reduce lsum over q-groups; write bf16 partials ----
  float ltot = lsum + __shfl_xor(lsum, 16, 64);
  ltot += __shfl_xor(ltot, 32, 64);
  char* R = split ? R1 : R0;
  unsigned int* PP = (unsigned int*)R;
  float* MLf = (float*)(R + 16777216);
  int mg = ((b * 32 + mtile) << 3) + w;
  if (lane < 16) MLf[mg * 16 + lane] = ltot;
#pragma unroll
  for (int ct = 0; ct < 16; ct++) {
    uint2 pk;
    pk.x = packbf2(acc[ct][0], acc[ct][1]);
    pk.y = packbf2(acc[ct][2], acc[ct][3]);
    *(uint2*)(PP + (mg * 16 + ct) * 128 + lane * 2) = pk;
  }
}

// ---------------- Kernel 5: combine splits, normalize, gamma*o + x -----------
__global__ __launch_bounds__(256) void kcombine(const char* __restrict__ R0, const char* __restrict__ R1,
                                                int nsplit, const float* __restrict__ x,
                                                const float* __restrict__ gma, float* __restrict__ out) {
  int tid = blockIdx.x * 256 + threadIdx.x;   // 4.19M threads, 2 outputs each
  const unsigned int* P0 = (const unsigned int*)R0;
  const float* ML0 = (const float*)(R0 + 16777216);
  int mg = tid >> 11;
  int ct = (tid >> 7) & 15;
  int lane = (tid >> 1) & 63;
  int rr = tid & 1;
  int b = mg >> 8, mtile = (mg >> 3) & 31, w = mg & 7;
  int m = mtile * 128 + w * 16 + (lane & 15);
  int c0 = ct * 16 + ((lane >> 4) & 3) * 4 + rr * 2;
  unsigned int p0 = P0[tid];
  float ox = __uint_as_float(p0 << 16);
  float oy = __uint_as_float(p0 & 0xffff0000u);
  float L = ML0[mg * 16 + (lane & 15)];
  if (nsplit == 2) {      // no shift: splits combine by plain addition
    const unsigned int* P1 = (const unsigned int*)R1;
    const float* ML1 = (const float*)(R1 + 16777216);
    unsigned int p1 = P1[tid];
    ox += __uint_as_float(p1 << 16);
    oy += __uint_as_float(p1 & 0xffff0000u);
    L += ML1[mg * 16 + (lane & 15)];
  }
  float sc = gma[0] / L;
  long o0 = ((long)(b * NC + c0)) * NN + m;
  out[o0] = ox * sc + x[o0];
  out[o0 + NN] = oy * sc + x[o0 + NN];
}

extern "C" void kernel_launch(void* const* d_in, const int* in_sizes, int n_in,
                              void* d_out, int out_size, void* d_ws, size_t ws_size,
                              hipStream_t stream) {
  const float* x   = (const float*)d_in[0];
  const float* Wq  = (const float*)d_in[1];
  const float* bq  = (const float*)d_in[2];
  const float* Wk  = (const float*)d_in[3];
  const float* bk  = (const float*)d_in[4];
  const float* Wv  = (const float*)d_in[5];
  const float* bv  = (const float*)d_in[6];
  const float* gma = (const float*)d_in[7];
  float* out = (float*)d_out;
  char* ws = (char*)d_ws;
  // layout (bytes): qT8 8.39M | kT8 8.39M | vO8 8.39M | fT 16.78M | Wc | bc | R1
  unsigned char* qT8 = (unsigned char*)(ws);
  unsigned char* kT8 = (unsigned char*)(ws + 8388608);
  unsigned char* vO8 = (unsigned char*)(ws + 16777216);
  bf16_t* fT = (bf16_t*)(ws + 25165824);
  bf16_t* Wc = (bf16_t*)(ws + 41943040);
  float*  bc = (float*)(ws + 42336256);
  char* R0 = ws + 25165824;         // reuses fT + Wc/bc (dead after kproj)
  char* R1 = ws + 42340352;
  size_t need2 = 42340352 + 16908288;
  int nsplit = (ws_size >= need2) ? 2 : 1;

  kconv_w<<<768, 256, 0, stream>>>(Wq, bq, Wk, bk, Wv, bv, Wc, bc);
  ktranspose<<<2048, 256, 0, stream>>>(x, fT);
  kproj<<<1536, 256, 0, stream>>>(Wc, bc, fT, qT8, kT8, vO8);
  kattn<<<256 * nsplit, 512, 0, stream>>>(qT8, kT8, vO8, R0, R1, 128 / nsplit);
  kcombine<<<16384, 256, 0, stream>>>(R0, R1, nsplit, x, gma, out);
}

// Round 13
// 171.690 us; speedup vs baseline: 3.0989x; 1.6771x over previous
//
#include <hip/hip_runtime.h>

typedef __bf16 bf16_t;
typedef __bf16 bf16x8 __attribute__((ext_vector_type(8)));
typedef float f32x16 __attribute__((ext_vector_type(16)));
typedef float f32x4 __attribute__((ext_vector_type(4)));

#define NB 8
#define NC 256
#define NN 4096

__device__ __forceinline__ f32x16 mfma32(bf16x8 a, bf16x8 b, f32x16 c) {
  return __builtin_amdgcn_mfma_f32_32x32x16_bf16(a, b, c, 0, 0, 0);
}

__device__ __forceinline__ f32x4 mfma16(uint2 a, uint2 b, f32x4 c) {
  union { uint2 u; long long l; } A, B;
  A.u = a; B.u = b;
  return __builtin_amdgcn_mfma_f32_16x16x32_fp8_fp8(A.l, B.l, c, 0, 0, 0);
}

__device__ __forceinline__ void gload_lds16(const void* g, void* l) {
  __builtin_amdgcn_global_load_lds((const __attribute__((address_space(1))) void*)g,
                                   (__attribute__((address_space(3))) void*)l, 16, 0, 0);
}

__device__ __forceinline__ unsigned int packbf2(float lo, float hi) {
  union { bf16_t h; unsigned short s; } a, b;
  a.h = (bf16_t)lo; b.h = (bf16_t)hi;
  return (unsigned int)a.s | ((unsigned int)b.s << 16);
}

__device__ __forceinline__ f32x16 fzero() {
  f32x16 z;
#pragma unroll
  for (int r = 0; r < 16; r++) z[r] = 0.f;
  return z;
}

// post-QK score scale: (1/W) * log2(e)  (softmax in exp2 domain, no shift: P~1)
#define QSCALE (0.015625f * 1.44269504088896f)

// ---------------- Kernel 1: convert weights to bf16 ---------------------------
__global__ void kconv_w(const float* __restrict__ Wq, const float* __restrict__ bq,
                        const float* __restrict__ Wk, const float* __restrict__ bk,
                        const float* __restrict__ Wv, const float* __restrict__ bv,
                        bf16_t* __restrict__ Wc, float* __restrict__ bc) {
  int idx = blockIdx.x * 256 + threadIdx.x;   // 768*256 total
  int d = idx >> 8;
  float w;
  if (d < 256)      w = Wq[idx];
  else if (d < 512) w = Wk[idx - 65536];
  else              w = Wv[idx - 131072];
  Wc[idx] = (bf16_t)w;
  if (idx < 768) {
    float v = idx < 256 ? bq[idx] : (idx < 512 ? bk[idx - 256] : bv[idx - 512]);
    bc[idx] = v;
  }
}

// ---------------- Kernel 2: x [B][C][N] f32 -> fT [B][N][C] bf16 -------------
__global__ void ktranspose(const float* __restrict__ x, bf16_t* __restrict__ fT) {
  __shared__ float tile[64][65];
  int bid = blockIdx.x;
  int b = bid >> 8;
  int r = bid & 255;
  int n0 = (r >> 2) * 64;
  int c0 = (r & 3) * 64;
  int t = threadIdx.x;
  const float* xb = x + ((long)b * NC + c0) * NN + n0;
  int lr = t >> 4;
  int lc = (t & 15) * 4;
#pragma unroll
  for (int i = 0; i < 4; i++) {
    float4 v4 = *(const float4*)(xb + (long)(lr + i * 16) * NN + lc);
    tile[lr + i * 16][lc + 0] = v4.x; tile[lr + i * 16][lc + 1] = v4.y;
    tile[lr + i * 16][lc + 2] = v4.z; tile[lr + i * 16][lc + 3] = v4.w;
  }
  __syncthreads();
  int nl = t >> 2;
  int cc = (t & 3) * 16;
  bf16_t* dst = fT + ((long)b * NN + n0 + nl) * NC + c0 + cc;
  union { bf16_t h[8]; uint4 u; } p0, p1;
#pragma unroll
  for (int j = 0; j < 8; j++) p0.h[j] = (bf16_t)tile[cc + j][nl];
#pragma unroll
  for (int j = 0; j < 8; j++) p1.h[j] = (bf16_t)tile[cc + 8 + j][nl];
  *(uint4*)dst = p0.u;
  *(uint4*)(dst + 8) = p1.u;
}

// ---------------- Kernel 3: projection GEMM [768,256]x[256,32768] ------------
// XCD-aware: the 6 blocks sharing one fT tile differ by 256 (same XCD -> L2 hit)
// outputs (fp8 e4m3), PAIRED frag-major for 16x16x32 mfma (16B/lane slots):
//   q tiles Kd[b][nt]: byte ((j>>1)*2+h)*1024 + l*16 + (j&1)*8 + e
//       = q[n=16h+(l&15)][c=j*32+((l>>4)&3)*8+e]
//   v tiles vD[b][nt]: byte (ct>>1)*1024 + l*16 + (ct&1)*8 + e
//       = v[c=ct*16+(l&15)][n=16(e>>2)+4((l>>4)&3)+(e&3)]
//   k as [B][N][C]
__global__ __launch_bounds__(256) void kproj(const bf16_t* __restrict__ Wc, const float* __restrict__ bc,
                                             const bf16_t* __restrict__ fT,
                                             unsigned char* __restrict__ qT8, unsigned char* __restrict__ kT8,
                                             unsigned char* __restrict__ vO8) {
  __shared__ bf16_t ft[128 * 256];  // XOR-swizzled rows, 64KB
  int bid = blockIdx.x;
  int mt = bid >> 8;          // 0..5
  int nb = bid & 255;         // 0..255: sharers of one fT tile are +256 apart
  int d0 = mt * 128;
  int gc0 = nb * 128;
  int b = gc0 >> 12;
  int n0 = gc0 & 4095;
  int t = threadIdx.x, lane = t & 63, w = t >> 6;
  int lm = lane & 31, g = lane >> 5;
  const bf16_t* ftb = fT + ((long)b * NN + n0) * NC;
#pragma unroll
  for (int i2 = 0; i2 < 16; i2++) {
    int call = w * 16 + i2;
    int p = call * 1024 + lane * 16;
    int n = p >> 9, cb = p & 511;
    int scb = cb ^ ((n & 7) << 4);
    gload_lds16(ftb + (long)n * NC + (scb >> 1), (char*)ft + call * 1024);
  }
  __syncthreads();

  f32x16 acc00 = fzero(), acc01 = fzero(), acc10 = fzero(), acc11 = fzero();
  int dbase = d0 + (w >> 1) * 64;
  int nbase = (w & 1) * 64;
  const bf16_t* wr = Wc + (long)dbase * NC;
#pragma unroll
  for (int j = 0; j < 16; j++) {
    int cc = j * 16 + g * 8;
    bf16x8 a0 = *(const bf16x8*)(wr + (long)lm * NC + cc);
    bf16x8 a1 = *(const bf16x8*)(wr + (long)(lm + 32) * NC + cc);
    int row0 = nbase + lm;
    bf16x8 b0 = *(const bf16x8*)((char*)ft + row0 * 512 + ((cc * 2) ^ ((row0 & 7) << 4)));
    int row1 = row0 + 32;
    bf16x8 b1 = *(const bf16x8*)((char*)ft + row1 * 512 + ((cc * 2) ^ ((row1 & 7) << 4)));
    acc00 = mfma32(a0, b0, acc00);
    acc01 = mfma32(a0, b1, acc01);
    acc10 = mfma32(a1, b0, acc10);
    acc11 = mfma32(a1, b1, acc11);
  }

  auto epi = [&](f32x16 a, int dt, int nt2) {
    int db = dbase + dt * 32;
    int colg = n0 + nbase + nt2 * 32 + lm;
    long tb = ((long)b * 128 + (colg >> 5)) * 8192;
    int n5 = colg & 31;
    if (mt >= 4) {        // v rows -> paired frag-major fp8 vD (byte stores)
      int q5 = (n5 >> 2) & 3;
      int e5 = ((n5 >> 4) << 2) + (n5 & 3);
      int ct0 = (db - 512) >> 4;
#pragma unroll
      for (int r = 0; r < 16; r++) {
        int d = db + (r & 3) + 8 * (r >> 2) + 4 * g;
        int ct = ct0 + (r >> 3);
        int kq = (r & 3) + 8 * ((r >> 2) & 1) + 4 * g;
        unsigned int f8 = __builtin_amdgcn_cvt_pk_fp8_f32(a[r] + bc[d], 0.f, 0, false);
        vO8[tb + (ct >> 1) * 1024 + (q5 * 16 + kq) * 16 + (ct & 1) * 8 + e5] = (unsigned char)f8;
      }
    } else if (mt < 2) {  // q rows -> paired frag-major fp8 Kd (u32 stores)
      int h = (n5 >> 4) & 1;
      int nr = n5 & 15;
      int j = db >> 5;
      long ob = tb + ((j >> 1) * 2 + h) * 1024 + (j & 1) * 8;
#pragma unroll
      for (int t4 = 0; t4 < 4; t4++) {
        int cb = db + 8 * t4 + 4 * g;
        unsigned int pk = __builtin_amdgcn_cvt_pk_fp8_f32(a[4 * t4 + 0] + bc[cb + 0],
                                                          a[4 * t4 + 1] + bc[cb + 1], 0, false);
        pk = __builtin_amdgcn_cvt_pk_fp8_f32(a[4 * t4 + 2] + bc[cb + 2],
                                             a[4 * t4 + 3] + bc[cb + 3], pk, true);
        *(unsigned int*)(qT8 + ob + (t4 * 16 + nr) * 16 + 4 * g) = pk;
      }
    } else {              // k rows -> [B][N][C] fp8 (pair ushort stores)
      unsigned char* dst = kT8 + ((long)b * NN + colg) * 256 - 256;
#pragma unroll
      for (int r2 = 0; r2 < 8; r2++) {
        int r = r2 * 2;
        int d = db + (r & 3) + 8 * (r >> 2) + 4 * g;
        unsigned int pk = __builtin_amdgcn_cvt_pk_fp8_f32(a[r] + bc[d], a[r + 1] + bc[d + 1], 0, false);
        *(unsigned short*)(dst + d) = (unsigned short)pk;
      }
    }
  };
  epi(acc00, 0, 0); epi(acc01, 0, 1); epi(acc10, 1, 0); epi(acc11, 1, 1);
}

// ---------------- Kernel 4: fp8 flash attention, 16x16 frags, 8 waves --------
// Exact R10 structure (dbuf, one barrier/iter); frag reads now PAIRED b128
// (8 reads for QK + 8 for PV per wave-tile, all contiguous 1KB/wave).
__global__ __launch_bounds__(512, 4) void kattn(const unsigned char* __restrict__ qT8,
                                                const unsigned char* __restrict__ kT8,
                                                const unsigned char* __restrict__ vO8,
                                                char* __restrict__ R0, char* __restrict__ R1, int iters) {
  __shared__ unsigned char Kt[2][8192];   // paired frag-major fp8
  __shared__ unsigned char Vt[2][8192];
  int bid = blockIdx.x;
  int b = bid & 7;
  int mtile = (bid >> 3) & 31;
  int split = bid >> 8;
  int nt0 = split * iters, ntE = nt0 + iters;
  int t = threadIdx.x, lane = t & 63, w = t >> 6;   // 8 waves
  int l4 = lane & 15, q = (lane >> 4) & 3;
  int mw = mtile * 128 + w * 16;
  const unsigned char* qb = qT8 + (long)b * 1048576;    // 128 tiles x 8192 B
  const unsigned char* vtb = vO8 + (long)b * 1048576;

  // B-frags of the flash-query (k-projection), col m = l4, k = q*8+e
  uint2 qf[8];
  const unsigned char* kb = kT8 + ((long)b * NN + mw + l4) * 256 + q * 8;
#pragma unroll
  for (int j = 0; j < 8; j++) qf[j] = *(const uint2*)(kb + j * 32);

  f32x4 acc[16];
#pragma unroll
  for (int ct = 0; ct < 16; ct++) acc[ct] = f32x4{0.f, 0.f, 0.f, 0.f};
  float lsum = 0.f;

  auto stageK = [&](int nt, int bufi) {
    gload_lds16(qb + (long)nt * 8192 + w * 1024 + lane * 16, &Kt[bufi][w * 1024]);
  };
  auto stageV = [&](int nt, int bufi) {
    gload_lds16(vtb + (long)nt * 8192 + w * 1024 + lane * 16, &Vt[bufi][w * 1024]);
  };

  stageK(nt0, 0);
  stageV(nt0, 0);
  __syncthreads();

  int buf = 0;
  for (int nt = nt0; nt < ntE; nt++) {
    bool more = nt + 1 < ntE;
    if (more) { stageK(nt + 1, buf ^ 1); stageV(nt + 1, buf ^ 1); }
    // ---- QK^T (swapped): paired b128 frag reads, 4 mfma per j2 ----
    __builtin_amdgcn_s_setprio(1);
    const unsigned char* kbase = &Kt[buf][0] + lane * 16;
    f32x4 s0 = f32x4{0.f, 0.f, 0.f, 0.f}, s1 = f32x4{0.f, 0.f, 0.f, 0.f};
#pragma unroll
    for (int j2 = 0; j2 < 4; j2++) {
      uint4 h0 = *(const uint4*)(kbase + (j2 * 2) * 1024);
      s0 = mfma16(make_uint2(h0.x, h0.y), qf[2 * j2], s0);
      s0 = mfma16(make_uint2(h0.z, h0.w), qf[2 * j2 + 1], s0);
      uint4 h1 = *(const uint4*)(kbase + (j2 * 2 + 1) * 1024);
      s1 = mfma16(make_uint2(h1.x, h1.y), qf[2 * j2], s1);
      s1 = mfma16(make_uint2(h1.z, h1.w), qf[2 * j2 + 1], s1);
    }
    __builtin_amdgcn_s_setprio(0);
    // ---- softmax (exp2 domain, no shift); lane holds 8 of 32 n's ----
    float e[8];
#pragma unroll
    for (int r = 0; r < 4; r++) {
      e[r] = __builtin_amdgcn_exp2f(s0[r] * QSCALE);
      e[4 + r] = __builtin_amdgcn_exp2f(s1[r] * QSCALE);
    }
    lsum += ((e[0] + e[1]) + (e[2] + e[3])) + ((e[4] + e[5]) + (e[6] + e[7]));
    uint2 pf;
    pf.x = __builtin_amdgcn_cvt_pk_fp8_f32(e[0], e[1], 0, false);
    pf.x = __builtin_amdgcn_cvt_pk_fp8_f32(e[2], e[3], pf.x, true);
    pf.y = __builtin_amdgcn_cvt_pk_fp8_f32(e[4], e[5], 0, false);
    pf.y = __builtin_amdgcn_cvt_pk_fp8_f32(e[6], e[7], pf.y, true);
    // ---- PV: paired b128 frag reads, 2 mfma per ct2 ----
    __builtin_amdgcn_s_setprio(1);
    const unsigned char* vbase = &Vt[buf][0] + lane * 16;
#pragma unroll
    for (int ct2 = 0; ct2 < 8; ct2++) {
      uint4 vv = *(const uint4*)(vbase + ct2 * 1024);
      acc[2 * ct2] = mfma16(make_uint2(vv.x, vv.y), pf, acc[2 * ct2]);
      acc[2 * ct2 + 1] = mfma16(make_uint2(vv.z, vv.w), pf, acc[2 * ct2 + 1]);
    }
    __builtin_amdgcn_s_setprio(0);
    __syncthreads();
    buf ^= 1;
  }
  // ---- epilogue: reduce lsum over q-groups; write bf16 partials ----
  float ltot = lsum + __shfl_xor(lsum, 16, 64);
  ltot += __shfl_xor(ltot, 32, 64);
  char* R = split ? R1 : R0;
  unsigned int* PP = (unsigned int*)R;
  float* MLf = (float*)(R + 16777216);
  int mg = ((b * 32 + mtile) << 3) + w;
  if (lane < 16) MLf[mg * 16 + lane] = ltot;
#pragma unroll
  for (int ct = 0; ct < 16; ct++) {
    uint2 pk;
    pk.x = packbf2(acc[ct][0], acc[ct][1]);
    pk.y = packbf2(acc[ct][2], acc[ct][3]);
    *(uint2*)(PP + (mg * 16 + ct) * 128 + lane * 2) = pk;
  }
}

// ---------------- Kernel 5: combine splits, normalize, gamma*o + x -----------
__global__ __launch_bounds__(256) void kcombine(const char* __restrict__ R0, const char* __restrict__ R1,
                                                int nsplit, const float* __restrict__ x,
                                                const float* __restrict__ gma, float* __restrict__ out) {
  int tid = blockIdx.x * 256 + threadIdx.x;   // 4.19M threads, 2 outputs each
  const unsigned int* P0 = (const unsigned int*)R0;
  const float* ML0 = (const float*)(R0 + 16777216);
  int mg = tid >> 11;
  int ct = (tid >> 7) & 15;
  int lane = (tid >> 1) & 63;
  int rr = tid & 1;
  int b = mg >> 8, mtile = (mg >> 3) & 31, w = mg & 7;
  int m = mtile * 128 + w * 16 + (lane & 15);
  int c0 = ct * 16 + ((lane >> 4) & 3) * 4 + rr * 2;
  unsigned int p0 = P0[tid];
  float ox = __uint_as_float(p0 << 16);
  float oy = __uint_as_float(p0 & 0xffff0000u);
  float L = ML0[mg * 16 + (lane & 15)];
  if (nsplit == 2) {      // no shift: splits combine by plain addition
    const unsigned int* P1 = (const unsigned int*)R1;
    const float* ML1 = (const float*)(R1 + 16777216);
    unsigned int p1 = P1[tid];
    ox += __uint_as_float(p1 << 16);
    oy += __uint_as_float(p1 & 0xffff0000u);
    L += ML1[mg * 16 + (lane & 15)];
  }
  float sc = gma[0] / L;
  long o0 = ((long)(b * NC + c0)) * NN + m;
  out[o0] = ox * sc + x[o0];
  out[o0 + NN] = oy * sc + x[o0 + NN];
}

extern "C" void kernel_launch(void* const* d_in, const int* in_sizes, int n_in,
                              void* d_out, int out_size, void* d_ws, size_t ws_size,
                              hipStream_t stream) {
  const float* x   = (const float*)d_in[0];
  const float* Wq  = (const float*)d_in[1];
  const float* bq  = (const float*)d_in[2];
  const float* Wk  = (const float*)d_in[3];
  const float* bk  = (const float*)d_in[4];
  const float* Wv  = (const float*)d_in[5];
  const float* bv  = (const float*)d_in[6];
  const float* gma = (const float*)d_in[7];
  float* out = (float*)d_out;
  char* ws = (char*)d_ws;
  // layout (bytes): qT8 8.39M | kT8 8.39M | vO8 8.39M | fT 16.78M | Wc | bc | R1
  unsigned char* qT8 = (unsigned char*)(ws);
  unsigned char* kT8 = (unsigned char*)(ws + 8388608);
  unsigned char* vO8 = (unsigned char*)(ws + 16777216);
  bf16_t* fT = (bf16_t*)(ws + 25165824);
  bf16_t* Wc = (bf16_t*)(ws + 41943040);
  float*  bc = (float*)(ws + 42336256);
  char* R0 = ws + 25165824;         // reuses fT + Wc/bc (dead after kproj)
  char* R1 = ws + 42340352;
  size_t need2 = 42340352 + 16908288;
  int nsplit = (ws_size >= need2) ? 2 : 1;

  kconv_w<<<768, 256, 0, stream>>>(Wq, bq, Wk, bk, Wv, bv, Wc, bc);
  ktranspose<<<2048, 256, 0, stream>>>(x, fT);
  kproj<<<1536, 256, 0, stream>>>(Wc, bc, fT, qT8, kT8, vO8);
  kattn<<<256 * nsplit, 512, 0, stream>>>(qT8, kT8, vO8, R0, R1, 128 / nsplit);
  kcombine<<<16384, 256, 0, stream>>>(R0, R1, nsplit, x, gma, out);
}